// Round 1
// baseline (6140.719 us; speedup 1.0000x reference)
//
#include <hip/hip_runtime.h>

#define USER_NUM 100000
#define ITEM_NUM 50000
#define N_NODES (USER_NUM + ITEM_NUM)
#define EMB 64
#define N_EDGES 2400000
#define N_LAYERS 3

// Copy user_emb || item_emb into ego0 (float4 vectorized).
__global__ void concat_kernel(const float* __restrict__ user_emb,
                              const float* __restrict__ item_emb,
                              float* __restrict__ ego) {
    // total floats = N_NODES*EMB = 9.6M -> 2.4M float4
    const int n4 = (N_NODES * EMB) / 4;
    const int user4 = (USER_NUM * EMB) / 4;
    for (int i = blockIdx.x * blockDim.x + threadIdx.x; i < n4;
         i += gridDim.x * blockDim.x) {
        float4 v;
        if (i < user4) {
            v = reinterpret_cast<const float4*>(user_emb)[i];
        } else {
            v = reinterpret_cast<const float4*>(item_emb)[i - user4];
        }
        reinterpret_cast<float4*>(ego)[i] = v;
    }
}

// COO SpMM scatter: y[rows[e]] += vals[e] * x[cols[e]]  (y must be pre-zeroed)
// 16 threads per edge, each handling 4 consecutive dims (float4 gather).
__global__ void spmm_atomic_kernel(const int* __restrict__ rows,
                                   const int* __restrict__ cols,
                                   const float* __restrict__ vals,
                                   const float* __restrict__ x,
                                   float* __restrict__ y) {
    const long long t = (long long)blockIdx.x * blockDim.x + threadIdx.x;
    const int edge = (int)(t >> 4);
    if (edge >= N_EDGES) return;
    const int dbase = (int)(t & 15) << 2;  // 0,4,...,60

    const int r = rows[edge];
    const int c = cols[edge];
    const float v = vals[edge];

    const float4 xv = *reinterpret_cast<const float4*>(x + (long long)c * EMB + dbase);
    float* yp = y + (long long)r * EMB + dbase;
    atomicAdd(yp + 0, v * xv.x);
    atomicAdd(yp + 1, v * xv.y);
    atomicAdd(yp + 2, v * xv.z);
    atomicAdd(yp + 3, v * xv.w);
}

// acc += scale * x  (float4 vectorized), over N_NODES*EMB floats
__global__ void axpy_kernel(const float* __restrict__ x, float* __restrict__ acc,
                            float scale) {
    const int n4 = (N_NODES * EMB) / 4;
    for (int i = blockIdx.x * blockDim.x + threadIdx.x; i < n4;
         i += gridDim.x * blockDim.x) {
        float4 xv = reinterpret_cast<const float4*>(x)[i];
        float4 av = reinterpret_cast<float4*>(acc)[i];
        av.x += scale * xv.x;
        av.y += scale * xv.y;
        av.z += scale * xv.z;
        av.w += scale * xv.w;
        reinterpret_cast<float4*>(acc)[i] = av;
    }
}

extern "C" void kernel_launch(void* const* d_in, const int* in_sizes, int n_in,
                              void* d_out, int out_size, void* d_ws, size_t ws_size,
                              hipStream_t stream) {
    const float* user_emb = (const float*)d_in[0];
    const float* item_emb = (const float*)d_in[1];
    const int*   adj_rows = (const int*)d_in[2];
    const int*   adj_cols = (const int*)d_in[3];
    const float* adj_vals = (const float*)d_in[4];
    float* out = (float*)d_out;

    const size_t nodeElems = (size_t)N_NODES * EMB;        // 9.6M floats
    float* bufA = (float*)d_ws;
    float* bufB = bufA + nodeElems;

    const int BLOCK = 256;
    const int elemGrid = 2048;  // grid-stride for 2.4M float4 elements

    // Zero the accumulator (d_out is poisoned before timing; never re-poisoned).
    hipMemsetAsync(d_out, 0, nodeElems * sizeof(float), stream);

    // ego0 = concat(user, item) -> bufA
    concat_kernel<<<elemGrid, BLOCK, 0, stream>>>(user_emb, item_emb, bufA);

    // SpMM grid: 16 threads/edge
    const long long spmmThreads = (long long)N_EDGES * 16;
    const int spmmGrid = (int)((spmmThreads + BLOCK - 1) / BLOCK);

    const float scale = 1.0f / N_LAYERS;

    float* cur = bufA;
    float* nxt = bufB;
    for (int layer = 0; layer < N_LAYERS; ++layer) {
        hipMemsetAsync(nxt, 0, nodeElems * sizeof(float), stream);
        spmm_atomic_kernel<<<spmmGrid, BLOCK, 0, stream>>>(adj_rows, adj_cols,
                                                           adj_vals, cur, nxt);
        axpy_kernel<<<elemGrid, BLOCK, 0, stream>>>(nxt, out, scale);
        float* tmp = cur; cur = nxt; nxt = tmp;
    }
}

// Round 2
// 593.433 us; speedup vs baseline: 10.3478x; 10.3478x over previous
//
#include <hip/hip_runtime.h>

#define USER_NUM 100000
#define ITEM_NUM 50000
#define N_NODES (USER_NUM + ITEM_NUM)
#define EMB 64
#define N_EDGES 2400000
#define N_LAYERS 3

#define SCAN_TILE 1024
#define SCAN_NB ((N_NODES + SCAN_TILE - 1) / SCAN_TILE)  // 147

// ---------------- common ----------------

// Copy user_emb || item_emb into ego0 (float4 vectorized).
__global__ void concat_kernel(const float* __restrict__ user_emb,
                              const float* __restrict__ item_emb,
                              float* __restrict__ ego) {
    const int n4 = (N_NODES * EMB) / 4;
    const int user4 = (USER_NUM * EMB) / 4;
    for (int i = blockIdx.x * blockDim.x + threadIdx.x; i < n4;
         i += gridDim.x * blockDim.x) {
        float4 v;
        if (i < user4) {
            v = reinterpret_cast<const float4*>(user_emb)[i];
        } else {
            v = reinterpret_cast<const float4*>(item_emb)[i - user4];
        }
        reinterpret_cast<float4*>(ego)[i] = v;
    }
}

// ---------------- CSR build ----------------

__global__ void hist_kernel(const int* __restrict__ rows, int* __restrict__ counts) {
    for (int e = blockIdx.x * blockDim.x + threadIdx.x; e < N_EDGES;
         e += gridDim.x * blockDim.x) {
        atomicAdd(&counts[rows[e]], 1);
    }
}

// pass A: per-tile (1024 elems) exclusive scan into offsets; tile sums -> partials
__global__ void scan_pass_a(const int* __restrict__ counts, int* __restrict__ offsets,
                            int* __restrict__ partials, int n) {
    __shared__ int lds[256];
    const int t = threadIdx.x;
    const int base = blockIdx.x * SCAN_TILE + t * 4;
    int v0 = 0, v1 = 0, v2 = 0, v3 = 0;
    if (base + 3 < n) {
        int4 q = *reinterpret_cast<const int4*>(counts + base);
        v0 = q.x; v1 = q.y; v2 = q.z; v3 = q.w;
    } else {
        if (base + 0 < n) v0 = counts[base + 0];
        if (base + 1 < n) v1 = counts[base + 1];
        if (base + 2 < n) v2 = counts[base + 2];
        if (base + 3 < n) v3 = counts[base + 3];
    }
    lds[t] = v0 + v1 + v2 + v3;
    __syncthreads();
    for (int off = 1; off < 256; off <<= 1) {
        int x = 0;
        if (t >= off) x = lds[t - off];
        __syncthreads();
        lds[t] += x;
        __syncthreads();
    }
    const int excl = (t == 0) ? 0 : lds[t - 1];
    if (t == 255) partials[blockIdx.x] = lds[255];
    const int o0 = excl, o1 = excl + v0, o2 = o1 + v1, o3 = o2 + v2;
    if (base + 0 < n) offsets[base + 0] = o0;
    if (base + 1 < n) offsets[base + 1] = o1;
    if (base + 2 < n) offsets[base + 2] = o2;
    if (base + 3 < n) offsets[base + 3] = o3;
}

// pass B: single block exclusive-scans partials[nb] in place (nb <= 256)
__global__ void scan_pass_b(int* __restrict__ partials, int nb) {
    __shared__ int lds[256];
    const int t = threadIdx.x;
    lds[t] = (t < nb) ? partials[t] : 0;
    __syncthreads();
    for (int off = 1; off < 256; off <<= 1) {
        int x = 0;
        if (t >= off) x = lds[t - off];
        __syncthreads();
        lds[t] += x;
        __syncthreads();
    }
    const int excl = (t == 0) ? 0 : lds[t - 1];
    if (t < nb) partials[t] = excl;
}

// pass C: add scanned tile bases; set offsets[n] = N_EDGES
__global__ void scan_pass_c(int* __restrict__ offsets, const int* __restrict__ partials,
                            int n) {
    const int base = blockIdx.x * SCAN_TILE + threadIdx.x * 4;
    const int add = partials[blockIdx.x];
    if (base + 0 < n) offsets[base + 0] += add;
    if (base + 1 < n) offsets[base + 1] += add;
    if (base + 2 < n) offsets[base + 2] += add;
    if (base + 3 < n) offsets[base + 3] += add;
    if (blockIdx.x == 0 && threadIdx.x == 0) offsets[n] = N_EDGES;
}

// scatter edges into row-sorted order (cursor must be pre-zeroed)
__global__ void scatter_kernel(const int* __restrict__ rows, const int* __restrict__ cols,
                               const float* __restrict__ vals,
                               const int* __restrict__ offsets, int* __restrict__ cursor,
                               int* __restrict__ cols_s, float* __restrict__ vals_s) {
    for (int e = blockIdx.x * blockDim.x + threadIdx.x; e < N_EDGES;
         e += gridDim.x * blockDim.x) {
        const int r = rows[e];
        const int k = atomicAdd(&cursor[r], 1);
        const int pos = offsets[r] + k;
        cols_s[pos] = cols[e];
        vals_s[pos] = vals[e];
    }
}

// ---------------- SpMM (gather, CSR) ----------------
// One wave per row; 4 subgroups of 16 lanes each process one edge/iter.
// Subgroup s, lane-in-sub l16: float4 covering dims [4*l16, 4*l16+4).
// Epilogue: y[r] = sum;  out[r] += scale * sum.
__global__ void spmm_gather_kernel(const int* __restrict__ offsets,
                                   const int* __restrict__ cols_s,
                                   const float* __restrict__ vals_s,
                                   const float* __restrict__ x,
                                   float* __restrict__ y,
                                   float* __restrict__ out, float scale) {
    const int wid = threadIdx.x >> 6;
    const int lane = threadIdx.x & 63;
    const int sub = lane >> 4;
    const int l16 = lane & 15;
    const int r = blockIdx.x * (blockDim.x >> 6) + wid;
    if (r >= N_NODES) return;

    const int start = offsets[r];
    const int end = offsets[r + 1];
    float4 s = {0.f, 0.f, 0.f, 0.f};
    for (int e = start + sub; e < end; e += 4) {
        const int c = cols_s[e];
        const float v = vals_s[e];
        const float4 xv =
            *reinterpret_cast<const float4*>(x + (size_t)c * EMB + 4 * l16);
        s.x += v * xv.x;
        s.y += v * xv.y;
        s.z += v * xv.z;
        s.w += v * xv.w;
    }
    // reduce across the 4 subgroups (lane bits 4 and 5)
    s.x += __shfl_xor(s.x, 16); s.y += __shfl_xor(s.y, 16);
    s.z += __shfl_xor(s.z, 16); s.w += __shfl_xor(s.w, 16);
    s.x += __shfl_xor(s.x, 32); s.y += __shfl_xor(s.y, 32);
    s.z += __shfl_xor(s.z, 32); s.w += __shfl_xor(s.w, 32);

    if (sub == 0) {
        const size_t o = (size_t)r * EMB + 4 * l16;
        *reinterpret_cast<float4*>(y + o) = s;
        float4 a = *reinterpret_cast<const float4*>(out + o);
        a.x += scale * s.x;
        a.y += scale * s.y;
        a.z += scale * s.z;
        a.w += scale * s.w;
        *reinterpret_cast<float4*>(out + o) = a;
    }
}

// ---------------- fallback (atomic scatter) ----------------

__global__ void spmm_atomic_kernel(const int* __restrict__ rows,
                                   const int* __restrict__ cols,
                                   const float* __restrict__ vals,
                                   const float* __restrict__ x,
                                   float* __restrict__ y) {
    const long long t = (long long)blockIdx.x * blockDim.x + threadIdx.x;
    const int edge = (int)(t >> 4);
    if (edge >= N_EDGES) return;
    const int dbase = (int)(t & 15) << 2;
    const int r = rows[edge];
    const int c = cols[edge];
    const float v = vals[edge];
    const float4 xv = *reinterpret_cast<const float4*>(x + (long long)c * EMB + dbase);
    float* yp = y + (long long)r * EMB + dbase;
    atomicAdd(yp + 0, v * xv.x);
    atomicAdd(yp + 1, v * xv.y);
    atomicAdd(yp + 2, v * xv.z);
    atomicAdd(yp + 3, v * xv.w);
}

__global__ void axpy_kernel(const float* __restrict__ x, float* __restrict__ acc,
                            float scale) {
    const int n4 = (N_NODES * EMB) / 4;
    for (int i = blockIdx.x * blockDim.x + threadIdx.x; i < n4;
         i += gridDim.x * blockDim.x) {
        float4 xv = reinterpret_cast<const float4*>(x)[i];
        float4 av = reinterpret_cast<float4*>(acc)[i];
        av.x += scale * xv.x;
        av.y += scale * xv.y;
        av.z += scale * xv.z;
        av.w += scale * xv.w;
        reinterpret_cast<float4*>(acc)[i] = av;
    }
}

// ---------------- launch ----------------

extern "C" void kernel_launch(void* const* d_in, const int* in_sizes, int n_in,
                              void* d_out, int out_size, void* d_ws, size_t ws_size,
                              hipStream_t stream) {
    const float* user_emb = (const float*)d_in[0];
    const float* item_emb = (const float*)d_in[1];
    const int*   adj_rows = (const int*)d_in[2];
    const int*   adj_cols = (const int*)d_in[3];
    const float* adj_vals = (const float*)d_in[4];
    float* out = (float*)d_out;

    const size_t nodeElems = (size_t)N_NODES * EMB;  // 9.6M floats
    const int BLOCK = 256;
    const float scale = 1.0f / N_LAYERS;

    // workspace layout
    float* bufA = (float*)d_ws;
    float* bufB = bufA + nodeElems;
    int*   cols_s = (int*)(bufB + nodeElems);
    float* vals_s = (float*)(cols_s + N_EDGES);
    int*   offsets = (int*)(vals_s + N_EDGES);    // N_NODES+1, padded to 150016
    int*   counts = offsets + 150016;             // N_NODES, padded to 150016
    int*   partials = counts + 150016;            // SCAN_NB (+pad)
    const size_t needed =
        ((char*)(partials + 256) - (char*)d_ws);

    // zero the output accumulator (harness poisons it; never re-poisons)
    hipMemsetAsync(d_out, 0, nodeElems * sizeof(float), stream);

    // ego0 = concat(user, item) -> bufA
    concat_kernel<<<2048, BLOCK, 0, stream>>>(user_emb, item_emb, bufA);

    if (ws_size >= needed) {
        // ---- CSR build ----
        hipMemsetAsync(counts, 0, 150016 * sizeof(int), stream);
        hist_kernel<<<2048, BLOCK, 0, stream>>>(adj_rows, counts);
        scan_pass_a<<<SCAN_NB, 256, 0, stream>>>(counts, offsets, partials, N_NODES);
        scan_pass_b<<<1, 256, 0, stream>>>(partials, SCAN_NB);
        scan_pass_c<<<SCAN_NB, 256, 0, stream>>>(offsets, partials, N_NODES);
        hipMemsetAsync(counts, 0, 150016 * sizeof(int), stream);  // reuse as cursor
        scatter_kernel<<<2048, BLOCK, 0, stream>>>(adj_rows, adj_cols, adj_vals,
                                                   offsets, counts, cols_s, vals_s);

        // ---- 3 gather-SpMM layers with fused accumulate ----
        const int rowsPerBlock = BLOCK / 64;  // 4
        const int spmmGrid = (N_NODES + rowsPerBlock - 1) / rowsPerBlock;
        float* cur = bufA;
        float* nxt = bufB;
        for (int layer = 0; layer < N_LAYERS; ++layer) {
            spmm_gather_kernel<<<spmmGrid, BLOCK, 0, stream>>>(offsets, cols_s, vals_s,
                                                               cur, nxt, out, scale);
            float* tmp = cur; cur = nxt; nxt = tmp;
        }
    } else {
        // ---- fallback: atomic scatter path (needs only 76.8 MB) ----
        const long long spmmThreads = (long long)N_EDGES * 16;
        const int spmmGrid = (int)((spmmThreads + BLOCK - 1) / BLOCK);
        float* cur = bufA;
        float* nxt = bufB;
        for (int layer = 0; layer < N_LAYERS; ++layer) {
            hipMemsetAsync(nxt, 0, nodeElems * sizeof(float), stream);
            spmm_atomic_kernel<<<spmmGrid, BLOCK, 0, stream>>>(adj_rows, adj_cols,
                                                               adj_vals, cur, nxt);
            axpy_kernel<<<2048, BLOCK, 0, stream>>>(nxt, out, scale);
            float* tmp = cur; cur = nxt; nxt = tmp;
        }
    }
}

// Round 3
// 579.047 us; speedup vs baseline: 10.6049x; 1.0248x over previous
//
#include <hip/hip_runtime.h>

#define USER_NUM 100000
#define ITEM_NUM 50000
#define N_NODES (USER_NUM + ITEM_NUM)
#define EMB 64
#define N_EDGES 2400000
#define N_LAYERS 3

#define SCAN_TILE 1024
#define SCAN_NB ((N_NODES + SCAN_TILE - 1) / SCAN_TILE)  // 147

typedef unsigned short u16;

__device__ __forceinline__ float bf2f(u16 h) {
    return __uint_as_float(((unsigned)h) << 16);
}
// round-to-nearest-even f32 -> bf16
__device__ __forceinline__ u16 f2bf(float f) {
    unsigned u = __float_as_uint(f);
    unsigned r = 0x7FFFu + ((u >> 16) & 1u);
    return (u16)((u + r) >> 16);
}

// ---------------- concat: user||item f32 -> bf16 ego0 ----------------
__global__ void concat_bf16_kernel(const float* __restrict__ user_emb,
                                   const float* __restrict__ item_emb,
                                   u16* __restrict__ ego) {
    const int n4 = (N_NODES * EMB) / 4;       // 2.4M groups of 4
    const int user4 = (USER_NUM * EMB) / 4;
    for (int i = blockIdx.x * blockDim.x + threadIdx.x; i < n4;
         i += gridDim.x * blockDim.x) {
        float4 v;
        if (i < user4) {
            v = reinterpret_cast<const float4*>(user_emb)[i];
        } else {
            v = reinterpret_cast<const float4*>(item_emb)[i - user4];
        }
        ushort4 o;
        o.x = f2bf(v.x); o.y = f2bf(v.y); o.z = f2bf(v.z); o.w = f2bf(v.w);
        reinterpret_cast<ushort4*>(ego)[i] = o;
    }
}

// ---------------- CSR build ----------------
__global__ void hist_kernel(const int* __restrict__ rows, int* __restrict__ counts) {
    for (int e = blockIdx.x * blockDim.x + threadIdx.x; e < N_EDGES;
         e += gridDim.x * blockDim.x) {
        atomicAdd(&counts[rows[e]], 1);
    }
}

__global__ void scan_pass_a(const int* __restrict__ counts, int* __restrict__ offsets,
                            int* __restrict__ partials, int n) {
    __shared__ int lds[256];
    const int t = threadIdx.x;
    const int base = blockIdx.x * SCAN_TILE + t * 4;
    int v0 = 0, v1 = 0, v2 = 0, v3 = 0;
    if (base + 3 < n) {
        int4 q = *reinterpret_cast<const int4*>(counts + base);
        v0 = q.x; v1 = q.y; v2 = q.z; v3 = q.w;
    } else {
        if (base + 0 < n) v0 = counts[base + 0];
        if (base + 1 < n) v1 = counts[base + 1];
        if (base + 2 < n) v2 = counts[base + 2];
        if (base + 3 < n) v3 = counts[base + 3];
    }
    lds[t] = v0 + v1 + v2 + v3;
    __syncthreads();
    for (int off = 1; off < 256; off <<= 1) {
        int x = 0;
        if (t >= off) x = lds[t - off];
        __syncthreads();
        lds[t] += x;
        __syncthreads();
    }
    const int excl = (t == 0) ? 0 : lds[t - 1];
    if (t == 255) partials[blockIdx.x] = lds[255];
    const int o0 = excl, o1 = excl + v0, o2 = o1 + v1, o3 = o2 + v2;
    if (base + 0 < n) offsets[base + 0] = o0;
    if (base + 1 < n) offsets[base + 1] = o1;
    if (base + 2 < n) offsets[base + 2] = o2;
    if (base + 3 < n) offsets[base + 3] = o3;
}

__global__ void scan_pass_b(int* __restrict__ partials, int nb) {
    __shared__ int lds[256];
    const int t = threadIdx.x;
    lds[t] = (t < nb) ? partials[t] : 0;
    __syncthreads();
    for (int off = 1; off < 256; off <<= 1) {
        int x = 0;
        if (t >= off) x = lds[t - off];
        __syncthreads();
        lds[t] += x;
        __syncthreads();
    }
    const int excl = (t == 0) ? 0 : lds[t - 1];
    if (t < nb) partials[t] = excl;
}

__global__ void scan_pass_c(int* __restrict__ offsets, const int* __restrict__ partials,
                            int n) {
    const int base = blockIdx.x * SCAN_TILE + threadIdx.x * 4;
    const int add = partials[blockIdx.x];
    if (base + 0 < n) offsets[base + 0] += add;
    if (base + 1 < n) offsets[base + 1] += add;
    if (base + 2 < n) offsets[base + 2] += add;
    if (base + 3 < n) offsets[base + 3] += add;
}

// Scatter edges into row-sorted order, packed (col, val_bits) per edge.
// Uses offsets[] itself as the cursor: after this kernel, offsets[r] = end(r),
// i.e. start(r) == offsets[r-1] (start(0) == 0).
__global__ void scatter_pack_kernel(const int* __restrict__ rows,
                                    const int* __restrict__ cols,
                                    const float* __restrict__ vals,
                                    int* __restrict__ offsets,
                                    int2* __restrict__ edges) {
    for (int e = blockIdx.x * blockDim.x + threadIdx.x; e < N_EDGES;
         e += gridDim.x * blockDim.x) {
        const int r = rows[e];
        const int pos = atomicAdd(&offsets[r], 1);
        edges[pos] = make_int2(cols[e], __float_as_int(vals[e]));
    }
}

// ---------------- SpMM (gather, CSR, bf16 in / bf16 out) ----------------
// One wave per row; 4 subgroups of 16 lanes, each processes one edge/iter.
// Lane l16 covers dims [4*l16, 4*l16+4) via an 8B ushort4 load.
__global__ void spmm_gather_bf16(const int* __restrict__ offsets_end,
                                 const int2* __restrict__ edges,
                                 const u16* __restrict__ x,
                                 u16* __restrict__ y) {
    const int wid = threadIdx.x >> 6;
    const int lane = threadIdx.x & 63;
    const int sub = lane >> 4;
    const int l16 = lane & 15;
    const int r = blockIdx.x * (blockDim.x >> 6) + wid;
    if (r >= N_NODES) return;

    const int start = (r == 0) ? 0 : offsets_end[r - 1];
    const int end = offsets_end[r];
    float4 s = {0.f, 0.f, 0.f, 0.f};
    for (int e = start + sub; e < end; e += 4) {
        const int2 ev = edges[e];
        const float v = __int_as_float(ev.y);
        const ushort4 xv =
            *reinterpret_cast<const ushort4*>(x + (size_t)ev.x * EMB + 4 * l16);
        s.x += v * bf2f(xv.x);
        s.y += v * bf2f(xv.y);
        s.z += v * bf2f(xv.z);
        s.w += v * bf2f(xv.w);
    }
    s.x += __shfl_xor(s.x, 16); s.y += __shfl_xor(s.y, 16);
    s.z += __shfl_xor(s.z, 16); s.w += __shfl_xor(s.w, 16);
    s.x += __shfl_xor(s.x, 32); s.y += __shfl_xor(s.y, 32);
    s.z += __shfl_xor(s.z, 32); s.w += __shfl_xor(s.w, 32);

    if (sub == 0) {
        ushort4 o;
        o.x = f2bf(s.x); o.y = f2bf(s.y); o.z = f2bf(s.z); o.w = f2bf(s.w);
        *reinterpret_cast<ushort4*>(y + (size_t)r * EMB + 4 * l16) = o;
    }
}

// ---------------- final combine: out = (e1+e2+e3)/3, full overwrite ----------------
__global__ void combine_kernel(const u16* __restrict__ b1, const u16* __restrict__ b2,
                               const u16* __restrict__ b3, float* __restrict__ out) {
    const int n4 = (N_NODES * EMB) / 4;
    const float s = 1.0f / N_LAYERS;
    for (int i = blockIdx.x * blockDim.x + threadIdx.x; i < n4;
         i += gridDim.x * blockDim.x) {
        const ushort4 a = reinterpret_cast<const ushort4*>(b1)[i];
        const ushort4 b = reinterpret_cast<const ushort4*>(b2)[i];
        const ushort4 c = reinterpret_cast<const ushort4*>(b3)[i];
        float4 o;
        o.x = (bf2f(a.x) + bf2f(b.x) + bf2f(c.x)) * s;
        o.y = (bf2f(a.y) + bf2f(b.y) + bf2f(c.y)) * s;
        o.z = (bf2f(a.z) + bf2f(b.z) + bf2f(c.z)) * s;
        o.w = (bf2f(a.w) + bf2f(b.w) + bf2f(c.w)) * s;
        reinterpret_cast<float4*>(out)[i] = o;
    }
}

// ---------------- launch ----------------
extern "C" void kernel_launch(void* const* d_in, const int* in_sizes, int n_in,
                              void* d_out, int out_size, void* d_ws, size_t ws_size,
                              hipStream_t stream) {
    const float* user_emb = (const float*)d_in[0];
    const float* item_emb = (const float*)d_in[1];
    const int*   adj_rows = (const int*)d_in[2];
    const int*   adj_cols = (const int*)d_in[3];
    const float* adj_vals = (const float*)d_in[4];
    float* out = (float*)d_out;

    const size_t nodeElems = (size_t)N_NODES * EMB;  // 9.6M
    const int BLOCK = 256;

    // workspace layout (all 8B-aligned)
    u16* b0 = (u16*)d_ws;                 // ego0 bf16, 19.2 MB
    u16* b1 = b0 + nodeElems;             // ego1
    u16* b2 = b1 + nodeElems;             // ego2
    u16* b3 = b2 + nodeElems;             // ego3
    int2* edges = (int2*)(b3 + nodeElems);       // 19.2 MB
    int* offsets = (int*)(edges + N_EDGES);      // 150016
    int* counts = offsets + 150016;              // 150016
    int* partials = counts + 150016;             // 256

    // ---- build inputs ----
    hipMemsetAsync(counts, 0, 150016 * sizeof(int), stream);
    concat_bf16_kernel<<<2048, BLOCK, 0, stream>>>(user_emb, item_emb, b0);
    hist_kernel<<<2048, BLOCK, 0, stream>>>(adj_rows, counts);
    scan_pass_a<<<SCAN_NB, 256, 0, stream>>>(counts, offsets, partials, N_NODES);
    scan_pass_b<<<1, 256, 0, stream>>>(partials, SCAN_NB);
    scan_pass_c<<<SCAN_NB, 256, 0, stream>>>(offsets, partials, N_NODES);
    scatter_pack_kernel<<<2048, BLOCK, 0, stream>>>(adj_rows, adj_cols, adj_vals,
                                                    offsets, edges);

    // ---- 3 gather-SpMM layers (bf16) ----
    const int rowsPerBlock = BLOCK / 64;  // 4
    const int spmmGrid = (N_NODES + rowsPerBlock - 1) / rowsPerBlock;
    spmm_gather_bf16<<<spmmGrid, BLOCK, 0, stream>>>(offsets, edges, b0, b1);
    spmm_gather_bf16<<<spmmGrid, BLOCK, 0, stream>>>(offsets, edges, b1, b2);
    spmm_gather_bf16<<<spmmGrid, BLOCK, 0, stream>>>(offsets, edges, b2, b3);

    // ---- out = (e1+e2+e3)/3 (fully overwrites d_out) ----
    combine_kernel<<<2048, BLOCK, 0, stream>>>(b1, b2, b3, out);
}